// Round 4
// baseline (137.502 us; speedup 1.0000x reference)
//
#include <hip/hip_runtime.h>
#include <cstdint>

#define D 1024
#define N_TOKENS 4096
#define N_SLOTS 8192
#define NEXP 8
#define NKT 16          // 1024 / BK(=64)
#define MAXT 80         // max 128-row tiles: 64 + 7 boundary
#define NTRF 128        // W2-transpose front y-rows in gemm1 grid (x16 = 2048 tiles)

typedef float f32x4 __attribute__((ext_vector_type(4)));
typedef __bf16 bf16x8 __attribute__((ext_vector_type(8)));
typedef __attribute__((address_space(3))) uint32_t lds_u32;
typedef __attribute__((address_space(1))) const uint32_t glb_u32;

__device__ __forceinline__ void gload_lds16(const void* g, void* l) {
  __builtin_amdgcn_global_load_lds((glb_u32*)g, (lds_u32*)l, 16, 0, 0);
}

__device__ __forceinline__ ushort f2bf(float f) {
  union { float f; uint32_t u; } c; c.f = f;
  uint32_t u = c.u;
  return (ushort)((u + 0x7FFFu + ((u >> 16) & 1u)) >> 16);
}

__device__ __forceinline__ float bf2f(ushort u) {
  union { uint32_t u; float f; } c; c.u = (uint32_t)u << 16;
  return c.f;
}

__device__ __forceinline__ bf16x8 lds_frag(const ushort* base, int row, int s) {
  return *(const bf16x8*)((const char*)base + row * 128 + ((s ^ (row & 7)) * 16));
}

// TPAD=66: transpose-tile row stride = 132 B = 33 banks (odd) -> the
// column-read (row step 4 per lane) spreads over 16 banks (4-way) instead of
// the 16-way conflict that stride 72 (36 banks, even) produced.
#define TPAD 66

// ---------------- fused prologue: routing + x-cast + out-zero + W1/W3 trans --
// block 0: routing; blocks 1..256: cast x fp32->bf16 + zero `out`;
// blocks 257..4352: W1/W3 transpose (fp32 [e][k][n] -> bf16 [e][n'][k] interleave)
// W2 transpose lives in gemm1 FRONT blocks (single-tile granularity).
__global__ void prep_k(const float* __restrict__ x, const int* __restrict__ ei,
                       const float* __restrict__ ew,
                       const float* __restrict__ w1, const float* __restrict__ w3,
                       float* __restrict__ hist_out, int* __restrict__ meta,
                       int* __restrict__ tok, float* __restrict__ wgt,
                       ushort* __restrict__ Xbf, ushort* __restrict__ w13t,
                       float* __restrict__ out) {
  int bid = blockIdx.x, t = threadIdx.x;
  if (bid == 0) {
    // deterministic routing: per-thread counts over contiguous 32-slot chunks
    __shared__ int cmat[256][8];   // 8 KB
    __shared__ int off[NEXP + 1];
#pragma unroll
    for (int e = 0; e < NEXP; e++) cmat[t][e] = 0;
    int base = t * 32;
#pragma unroll 4
    for (int j = 0; j < 32; j++) cmat[t][ei[base + j]]++;
    __syncthreads();
    if (t < NEXP) {
      int run = 0;
      for (int i = 0; i < 256; i++) { int v = cmat[i][t]; cmat[i][t] = run; run += v; }
      meta[8 + t] = run;   // expert totals (temp)
    }
    __syncthreads();
    if (t == 0) {
      int s = 0;
      for (int e = 0; e < NEXP; e++) { off[e] = s; s += meta[8 + e]; }
      off[NEXP] = s;
      int nt = 0;
      for (int e = 0; e < NEXP; e++)
        for (int r = off[e]; r < off[e + 1]; r += 128)
          if (nt < MAXT) {
            meta[16 + nt] = e;
            meta[96 + nt] = r;
            int re = off[e + 1]; if (r + 128 < re) re = r + 128;
            meta[176 + nt] = re;
            nt++;
          }
      meta[0] = nt;
      for (int e = 0; e < NEXP; e++) hist_out[e] = (float)meta[8 + e];
    }
    __syncthreads();
    // deterministic scatter; record token id and routing weight per position
#pragma unroll 4
    for (int j = 0; j < 32; j++) {
      int slot = base + j;
      int e = ei[slot];
      int p = off[e] + cmat[t][e]++;
      tok[p] = slot >> 1;
      wgt[p] = ew[slot];
    }
  } else if (bid <= 256) {
    // cast x -> bf16, token order; also zero the fp32 out buffer (gemm2
    // scatters into it with atomicAdd). 16384 elems per block each.
    int cb = bid - 1;
    const float4* xs = (const float4*)x + (size_t)cb * 4096;
    ushort4* xd = (ushort4*)Xbf + (size_t)cb * 4096;
    float4* oz = (float4*)out + (size_t)cb * 4096;
    float4 z; z.x = 0.f; z.y = 0.f; z.z = 0.f; z.w = 0.f;
#pragma unroll
    for (int i = 0; i < 16; i++) {
      float4 v = xs[i * 256 + t];
      ushort4 o;
      o.x = f2bf(v.x); o.y = f2bf(v.y); o.z = f2bf(v.z); o.w = f2bf(v.w);
      xd[i * 256 + t] = o;
      oz[i * 256 + t] = z;
    }
  } else {
    int wb = bid - 257;
    int z = wb >> 8, rem = wb & 255;
    int kb = rem >> 4, nb = rem & 15;
    int which = z >> 3, e = z & 7;           // which: 0=W1, 1=W3
    const float* src = (which == 0 ? w1 : w3) + (size_t)e * D * D;
    ushort* dst = w13t + (size_t)e * 2048 * D;
    __shared__ ushort tile[64][TPAD];
    int k0 = kb * 64, n0 = nb * 64;
    int r = t >> 4, c = t & 15;
#pragma unroll
    for (int rep = 0; rep < 4; rep++) {
      int krow = rep * 16 + r;
      float4 v = *(const float4*)(src + (size_t)(k0 + krow) * D + n0 + c * 4);
      tile[krow][c * 4 + 0] = f2bf(v.x);
      tile[krow][c * 4 + 1] = f2bf(v.y);
      tile[krow][c * 4 + 2] = f2bf(v.z);
      tile[krow][c * 4 + 3] = f2bf(v.w);
    }
    __syncthreads();
#pragma unroll
    for (int rep = 0; rep < 4; rep++) {
      int lr = rep * 16 + r;
      int nrow = n0 + lr;
      ushort4 o;
      o.x = tile[c * 4 + 0][lr];
      o.y = tile[c * 4 + 1][lr];
      o.z = tile[c * 4 + 2][lr];
      o.w = tile[c * 4 + 3][lr];
      int crow = ((nrow >> 4) << 5) + ((which == 1) ? 16 : 0) + (nrow & 15);
      *(ushort4*)(dst + (size_t)crow * D + k0 + c * 4) = o;
    }
  }
}

// ---- GEMM1: tile 128(M) x 128(Ni), BK=64, 4 waves 2x2, wave 64x64,
// single-buffered LDS (32 KB) for 4 blocks/CU TLP latency hiding (proven
// 687 TF = the 2-phase structural ceiling; dbuf+vmcnt regressed, see R1).
// Grid FRONT (blockIdx.y < NTRF): W2 fp32->bf16 transpose at SINGLE-TILE
// granularity (2048 blocks x ~1.3 us). R3's 256 x 10-us serial blocks pinned
// 25% of block slots for 10 us (+6 us tax); short blocks churn slots so the
// GEMM backfills immediately. W2t consumed only by gemm2 (stream-ordered). ----
__global__ __launch_bounds__(256, 4) void gemm1_k(
    const ushort* __restrict__ Xbf, const ushort* __restrict__ W13t,
    ushort* __restrict__ H, const int* __restrict__ tok,
    const int* __restrict__ meta,
    const float* __restrict__ w2, ushort* __restrict__ W2t) {
  __shared__ ushort sA[128 * 64];
  __shared__ ushort sB[128 * 64];
  int tm = blockIdx.y;
  int tid = threadIdx.x;

  if (tm < NTRF) {
    // ---- W2 transpose front-path: one 64x64 tile per block ----
    int T = tm * 16 + blockIdx.x;        // 0..2047
    int e = T >> 8, rem = T & 255;
    int kb = rem >> 4, nb = rem & 15;
    const float* src = w2 + (size_t)e * D * D;
    ushort* dst = W2t + (size_t)e * D * D;
    ushort (*tile)[TPAD] = (ushort(*)[TPAD])&sA[0];   // 8.25 KB overlay scratch
    int r = tid >> 4, c = tid & 15;
    int k0 = kb * 64, n0 = nb * 64;
#pragma unroll
    for (int rep = 0; rep < 4; rep++) {
      int krow = rep * 16 + r;
      float4 v = *(const float4*)(src + (size_t)(k0 + krow) * D + n0 + c * 4);
      tile[krow][c * 4 + 0] = f2bf(v.x);
      tile[krow][c * 4 + 1] = f2bf(v.y);
      tile[krow][c * 4 + 2] = f2bf(v.z);
      tile[krow][c * 4 + 3] = f2bf(v.w);
    }
    __syncthreads();
#pragma unroll
    for (int rep = 0; rep < 4; rep++) {
      int lr = rep * 16 + r;
      ushort4 o;
      o.x = tile[c * 4 + 0][lr];
      o.y = tile[c * 4 + 1][lr];
      o.z = tile[c * 4 + 2][lr];
      o.w = tile[c * 4 + 3][lr];
      *(ushort4*)(dst + (size_t)(n0 + lr) * D + k0 + c * 4) = o;
    }
    return;
  }
  tm -= NTRF;
  if (tm >= meta[0]) return;

  int e = meta[16 + tm], r0 = meta[96 + tm], rend = meta[176 + tm];
  int n0i = blockIdx.x * 128;
  int lane = tid & 63, wid = tid >> 6;
  int wm = wid >> 1, wn = wid & 1;

  const char* gX = (const char*)Xbf;
  const char* gB = (const char*)(W13t + (size_t)e * 2048 * D);

  int prow = tid >> 3, pslot = tid & 7;
  size_t arow[4];
  int brow[4], phys[4];
#pragma unroll
  for (int i = 0; i < 4; i++) {
    int row = i * 32 + prow;
    int gr = r0 + row; if (gr > N_SLOTS - 1) gr = N_SLOTS - 1;
    arow[i] = (size_t)tok[gr] * 2048;
    brow[i] = n0i + row;
    phys[i] = (pslot ^ (row & 7)) * 16;
  }

  f32x4 acc[4][4] = {};

  for (int kt = 0; kt < NKT; kt++) {
    int kb = kt * 128;
#pragma unroll
    for (int i = 0; i < 4; i++) {
      gload_lds16(gX + arow[i] + kb + phys[i], (char*)sA + (i * 256 + tid) * 16);
      gload_lds16(gB + (size_t)brow[i] * 2048 + kb + phys[i],
                  (char*)sB + (i * 256 + tid) * 16);
    }
    __syncthreads();   // vmcnt(0) drain + barrier: tile ready
#pragma unroll
    for (int kk = 0; kk < 2; kk++) {
      int s = kk * 4 + (lane >> 4);
      bf16x8 a[4], b[4];
#pragma unroll
      for (int mf = 0; mf < 4; mf++)
        a[mf] = lds_frag(sA, wm * 64 + mf * 16 + (lane & 15), s);
#pragma unroll
      for (int nf = 0; nf < 4; nf++)
        b[nf] = lds_frag(sB, wn * 64 + nf * 16 + (lane & 15), s);
#pragma unroll
      for (int mf = 0; mf < 4; mf++)
#pragma unroll
        for (int nf = 0; nf < 4; nf++)
          acc[mf][nf] = __builtin_amdgcn_mfma_f32_16x16x32_bf16(a[mf], b[nf], acc[mf][nf], 0, 0, 0);
    }
    __syncthreads();   // all reads done; LDS free for next stage
  }

  // epilogue: nf pairs (W1,W3) -> silu(g)*u
  int cb = (n0i >> 1) + wn * 32 + (lane & 15);
#pragma unroll
  for (int mf = 0; mf < 4; mf++)
#pragma unroll
    for (int v = 0; v < 4; v++) {
      int r = r0 + wm * 64 + mf * 16 + (lane >> 4) * 4 + v;
      if (r >= rend) continue;
#pragma unroll
      for (int p = 0; p < 2; p++) {
        float g = acc[mf][2 * p][v], u = acc[mf][2 * p + 1][v];
        float hv = g / (1.f + __expf(-g)) * u;
        H[(size_t)r * D + cb + p * 16] = f2bf(hv);
      }
    }
}

// ---- GEMM2: tile 128(M) x 128(N), BK=64, 4 waves 2x2, wave 64x64,
// single-buffered (32 KB, 4 blocks/CU). Epilogue scatters w*acc directly
// into fp32 `out` via atomicAdd (exactly 2 addends per token element) —
// replaces the Y buffer + combine kernel. out is zeroed by prep. ----
__global__ __launch_bounds__(256, 4) void gemm2_k(
    const ushort* __restrict__ Hm, const ushort* __restrict__ W2t,
    const int* __restrict__ tok, const float* __restrict__ wgt,
    float* __restrict__ out, const int* __restrict__ meta) {
  __shared__ ushort sA[128 * 64];
  __shared__ ushort sB[128 * 64];
  int tm = blockIdx.y;
  if (tm >= meta[0]) return;
  int e = meta[16 + tm], r0 = meta[96 + tm], rend = meta[176 + tm];
  int n0 = blockIdx.x * 128;
  int tid = threadIdx.x, lane = tid & 63, wid = tid >> 6;
  int wm = wid >> 1, wn = wid & 1;

  const char* gH = (const char*)Hm;
  const char* gB = (const char*)(W2t + (size_t)e * D * D);

  int prow = tid >> 3, pslot = tid & 7;
  size_t arow[4];
  int brow[4], phys[4];
#pragma unroll
  for (int i = 0; i < 4; i++) {
    int row = i * 32 + prow;
    int gr = r0 + row; if (gr > N_SLOTS - 1) gr = N_SLOTS - 1;
    arow[i] = (size_t)gr * 2048;
    brow[i] = n0 + row;
    phys[i] = (pslot ^ (row & 7)) * 16;
  }

  f32x4 acc[4][4] = {};

  for (int kt = 0; kt < NKT; kt++) {
    int kb = kt * 128;
#pragma unroll
    for (int i = 0; i < 4; i++) {
      gload_lds16(gH + arow[i] + kb + phys[i], (char*)sA + (i * 256 + tid) * 16);
      gload_lds16(gB + (size_t)brow[i] * 2048 + kb + phys[i],
                  (char*)sB + (i * 256 + tid) * 16);
    }
    __syncthreads();
#pragma unroll
    for (int kk = 0; kk < 2; kk++) {
      int s = kk * 4 + (lane >> 4);
      bf16x8 a[4], b[4];
#pragma unroll
      for (int mf = 0; mf < 4; mf++)
        a[mf] = lds_frag(sA, wm * 64 + mf * 16 + (lane & 15), s);
#pragma unroll
      for (int nf = 0; nf < 4; nf++)
        b[nf] = lds_frag(sB, wn * 64 + nf * 16 + (lane & 15), s);
#pragma unroll
      for (int mf = 0; mf < 4; mf++)
#pragma unroll
        for (int nf = 0; nf < 4; nf++)
          acc[mf][nf] = __builtin_amdgcn_mfma_f32_16x16x32_bf16(a[mf], b[nf], acc[mf][nf], 0, 0, 0);
    }
    __syncthreads();
  }

  // epilogue: out[tok[r]] += wgt[r] * acc  (fp32 atomics, device scope)
#pragma unroll
  for (int mf = 0; mf < 4; mf++)
#pragma unroll
    for (int v = 0; v < 4; v++) {
      int r = r0 + wm * 64 + mf * 16 + (lane >> 4) * 4 + v;
      if (r >= rend) continue;
      int tokid = tok[r];
      float w = wgt[r];
      float* orow = out + (size_t)tokid * D + n0 + wn * 64 + (lane & 15);
#pragma unroll
      for (int nf = 0; nf < 4; nf++)
        atomicAdd(orow + nf * 16, w * acc[mf][nf][v]);
    }
}

extern "C" void kernel_launch(void* const* d_in, const int* in_sizes, int n_in,
                              void* d_out, int out_size, void* d_ws, size_t ws_size,
                              hipStream_t stream) {
  const float* x  = (const float*)d_in[0];
  const float* ew = (const float*)d_in[1];
  const int*   ei = (const int*)d_in[2];
  const float* w1 = (const float*)d_in[3];
  const float* w3 = (const float*)d_in[4];
  const float* w2 = (const float*)d_in[5];
  float* out = (float*)d_out;

  char* ws = (char*)d_ws;
  int*    meta = (int*)ws;                            // 4 KB
  int*    tok  = (int*)(ws + 4096);                   // 32 KB
  float*  wgt  = (float*)(ws + 4096 + 32768);         // 32 KB
  ushort* Xbf  = (ushort*)(ws + (1ull << 20));        // [1,9) MB (token order)
  ushort* W13t = (ushort*)(ws + (9ull << 20));        // [9,41) MB (interleaved)
  ushort* W2t  = (ushort*)(ws + (41ull << 20));       // [41,57) MB (by gemm1 front)
  ushort* Hm   = (ushort*)(ws + (57ull << 20));       // [57,73) MB (slot order)

  prep_k<<<4353, 256, 0, stream>>>(x, ei, ew, w1, w3,
                                   out + (size_t)N_TOKENS * D, meta, tok, wgt,
                                   Xbf, W13t, out);
  gemm1_k<<<dim3(16, NTRF + MAXT), 256, 0, stream>>>(Xbf, W13t, Hm, tok, meta, w2, W2t);
  gemm2_k<<<dim3(8, MAXT), 256, 0, stream>>>(Hm, W2t, tok, wgt, out, meta);
}

// Round 5
// 116.210 us; speedup vs baseline: 1.1832x; 1.1832x over previous
//
#include <hip/hip_runtime.h>
#include <cstdint>

#define D 1024
#define N_TOKENS 4096
#define N_SLOTS 8192
#define NEXP 8
#define NKT 16          // 1024 / BK(=64)
#define MAXT 80         // max 128-row tiles: 64 + 7 boundary
#define NTRB 4          // W2-transpose front y-rows (x16 = 64 blocks x 32 tiles)

typedef float f32x4 __attribute__((ext_vector_type(4)));
typedef __bf16 bf16x8 __attribute__((ext_vector_type(8)));
typedef __attribute__((address_space(3))) uint32_t lds_u32;
typedef __attribute__((address_space(1))) const uint32_t glb_u32;

__device__ __forceinline__ void gload_lds16(const void* g, void* l) {
  __builtin_amdgcn_global_load_lds((glb_u32*)g, (lds_u32*)l, 16, 0, 0);
}

__device__ __forceinline__ ushort f2bf(float f) {
  union { float f; uint32_t u; } c; c.f = f;
  uint32_t u = c.u;
  return (ushort)((u + 0x7FFFu + ((u >> 16) & 1u)) >> 16);
}

__device__ __forceinline__ float bf2f(ushort u) {
  union { uint32_t u; float f; } c; c.u = (uint32_t)u << 16;
  return c.f;
}

__device__ __forceinline__ bf16x8 lds_frag(const ushort* base, int row, int s) {
  return *(const bf16x8*)((const char*)base + row * 128 + ((s ^ (row & 7)) * 16));
}

// TPAD=66: transpose-tile row stride = 132 B = 33 banks (odd) -> the
// column-read (row step 4 per lane) spreads over 16 banks (4-way) instead of
// the 16-way conflict that stride 72 (36 banks, even) produced.
#define TPAD 66

// ---------------- fused prologue: routing + x-cast + W1/W3 transpose --------
// block 0: routing; blocks 1..256: cast x fp32->bf16 (token order);
// blocks 257..4352: W1/W3 transpose (fp32 [e][k][n] -> bf16 [e][n'][k] interleave)
// W2 transpose lives in gemm1 FRONT blocks (64 long-running blocks).
__global__ void prep_k(const float* __restrict__ x, const int* __restrict__ ei,
                       const float* __restrict__ ew,
                       const float* __restrict__ w1, const float* __restrict__ w3,
                       float* __restrict__ hist_out, int* __restrict__ meta,
                       int* __restrict__ tok, int* __restrict__ smap,
                       ushort* __restrict__ Xbf, ushort* __restrict__ w13t) {
  int bid = blockIdx.x, t = threadIdx.x;
  if (bid == 0) {
    // deterministic routing: per-thread counts over contiguous 32-slot chunks
    __shared__ int cmat[256][8];   // 8 KB
    __shared__ int off[NEXP + 1];
#pragma unroll
    for (int e = 0; e < NEXP; e++) cmat[t][e] = 0;
    int base = t * 32;
#pragma unroll 4
    for (int j = 0; j < 32; j++) cmat[t][ei[base + j]]++;
    __syncthreads();
    if (t < NEXP) {
      int run = 0;
      for (int i = 0; i < 256; i++) { int v = cmat[i][t]; cmat[i][t] = run; run += v; }
      meta[8 + t] = run;   // expert totals (temp)
    }
    __syncthreads();
    if (t == 0) {
      int s = 0;
      for (int e = 0; e < NEXP; e++) { off[e] = s; s += meta[8 + e]; }
      off[NEXP] = s;
      int nt = 0;
      for (int e = 0; e < NEXP; e++)
        for (int r = off[e]; r < off[e + 1]; r += 128)
          if (nt < MAXT) {
            meta[16 + nt] = e;
            meta[96 + nt] = r;
            int re = off[e + 1]; if (r + 128 < re) re = r + 128;
            meta[176 + nt] = re;
            nt++;
          }
      meta[0] = nt;
      for (int e = 0; e < NEXP; e++) hist_out[e] = (float)meta[8 + e];
    }
    __syncthreads();
    // deterministic scatter; also record inverse map slot -> position
#pragma unroll 4
    for (int j = 0; j < 32; j++) {
      int slot = base + j;
      int e = ei[slot];
      int p = off[e] + cmat[t][e]++;
      tok[p] = slot >> 1;
      smap[slot] = p;
    }
  } else if (bid <= 256) {
    // cast x -> bf16, token order. 16384 elems per block.
    int cb = bid - 1;
    const float4* xs = (const float4*)x + (size_t)cb * 4096;
    ushort4* xd = (ushort4*)Xbf + (size_t)cb * 4096;
#pragma unroll
    for (int i = 0; i < 16; i++) {
      float4 v = xs[i * 256 + t];
      ushort4 o;
      o.x = f2bf(v.x); o.y = f2bf(v.y); o.z = f2bf(v.z); o.w = f2bf(v.w);
      xd[i * 256 + t] = o;
    }
  } else {
    int wb = bid - 257;
    int z = wb >> 8, rem = wb & 255;
    int kb = rem >> 4, nb = rem & 15;
    int which = z >> 3, e = z & 7;           // which: 0=W1, 1=W3
    const float* src = (which == 0 ? w1 : w3) + (size_t)e * D * D;
    ushort* dst = w13t + (size_t)e * 2048 * D;
    __shared__ ushort tile[64][TPAD];
    int k0 = kb * 64, n0 = nb * 64;
    int r = t >> 4, c = t & 15;
#pragma unroll
    for (int rep = 0; rep < 4; rep++) {
      int krow = rep * 16 + r;
      float4 v = *(const float4*)(src + (size_t)(k0 + krow) * D + n0 + c * 4);
      tile[krow][c * 4 + 0] = f2bf(v.x);
      tile[krow][c * 4 + 1] = f2bf(v.y);
      tile[krow][c * 4 + 2] = f2bf(v.z);
      tile[krow][c * 4 + 3] = f2bf(v.w);
    }
    __syncthreads();
#pragma unroll
    for (int rep = 0; rep < 4; rep++) {
      int lr = rep * 16 + r;
      int nrow = n0 + lr;
      ushort4 o;
      o.x = tile[c * 4 + 0][lr];
      o.y = tile[c * 4 + 1][lr];
      o.z = tile[c * 4 + 2][lr];
      o.w = tile[c * 4 + 3][lr];
      int crow = ((nrow >> 4) << 5) + ((which == 1) ? 16 : 0) + (nrow & 15);
      *(ushort4*)(dst + (size_t)crow * D + k0 + c * 4) = o;
    }
  }
}

// ---- GEMM1: tile 128(M) x 128(Ni), BK=64, 4 waves 2x2, wave 64x64,
// single-buffered LDS (32 KB) for 4 blocks/CU TLP latency hiding (proven
// 687 TF = the 2-phase grouped ceiling; dbuf+vmcnt regressed, see R1).
// Grid FRONT (blockIdx.y < NTRB): W2 fp32->bf16 transpose, 64 blocks x 32
// tiles (~32 us each, < GEMM duration). Cost model: tax ~= n_blk x dur /
// capacity + BW contention -> minimized by FEW blocks running LONG.
// (R3: 256 blk x 10 us = 6.2 us tax; R4's 2048 x 1-tile serialized the whole
// machine = 10 us tax.) W2t consumed only by gemm2 (stream-ordered). ----
__global__ __launch_bounds__(256, 4) void gemm1_k(
    const ushort* __restrict__ Xbf, const ushort* __restrict__ W13t,
    ushort* __restrict__ H, const int* __restrict__ tok,
    const int* __restrict__ meta,
    const float* __restrict__ w2, ushort* __restrict__ W2t) {
  __shared__ ushort sA[128 * 64];
  __shared__ ushort sB[128 * 64];
  int tm = blockIdx.y;
  int tid = threadIdx.x;

  if (tm < NTRB) {
    // ---- W2 transpose front-path: 32 sequential 64x64 tiles per block ----
    int gid = tm * 16 + blockIdx.x;                    // 0..63
    ushort (*tile)[TPAD] = (ushort(*)[TPAD])&sA[0];    // 8.25 KB overlay scratch
    int r = tid >> 4, c = tid & 15;
    for (int i = 0; i < 32; i++) {
      int T = gid * 32 + i;                            // 0..2047
      int e = T >> 8, rem = T & 255;
      int kb = rem >> 4, nb = rem & 15;
      const float* src = w2 + (size_t)e * D * D;
      ushort* dst = W2t + (size_t)e * D * D;
      int k0 = kb * 64, n0 = nb * 64;
      __syncthreads();
#pragma unroll
      for (int rep = 0; rep < 4; rep++) {
        int krow = rep * 16 + r;
        float4 v = *(const float4*)(src + (size_t)(k0 + krow) * D + n0 + c * 4);
        tile[krow][c * 4 + 0] = f2bf(v.x);
        tile[krow][c * 4 + 1] = f2bf(v.y);
        tile[krow][c * 4 + 2] = f2bf(v.z);
        tile[krow][c * 4 + 3] = f2bf(v.w);
      }
      __syncthreads();
#pragma unroll
      for (int rep = 0; rep < 4; rep++) {
        int lr = rep * 16 + r;
        ushort4 o;
        o.x = tile[c * 4 + 0][lr];
        o.y = tile[c * 4 + 1][lr];
        o.z = tile[c * 4 + 2][lr];
        o.w = tile[c * 4 + 3][lr];
        *(ushort4*)(dst + (size_t)(n0 + lr) * D + k0 + c * 4) = o;
      }
    }
    return;
  }
  tm -= NTRB;
  if (tm >= meta[0]) return;

  int e = meta[16 + tm], r0 = meta[96 + tm], rend = meta[176 + tm];
  int n0i = blockIdx.x * 128;
  int lane = tid & 63, wid = tid >> 6;
  int wm = wid >> 1, wn = wid & 1;

  const char* gX = (const char*)Xbf;
  const char* gB = (const char*)(W13t + (size_t)e * 2048 * D);

  int prow = tid >> 3, pslot = tid & 7;
  size_t arow[4];
  int brow[4], phys[4];
#pragma unroll
  for (int i = 0; i < 4; i++) {
    int row = i * 32 + prow;
    int gr = r0 + row; if (gr > N_SLOTS - 1) gr = N_SLOTS - 1;
    arow[i] = (size_t)tok[gr] * 2048;
    brow[i] = n0i + row;
    phys[i] = (pslot ^ (row & 7)) * 16;
  }

  f32x4 acc[4][4] = {};

  for (int kt = 0; kt < NKT; kt++) {
    int kb = kt * 128;
#pragma unroll
    for (int i = 0; i < 4; i++) {
      gload_lds16(gX + arow[i] + kb + phys[i], (char*)sA + (i * 256 + tid) * 16);
      gload_lds16(gB + (size_t)brow[i] * 2048 + kb + phys[i],
                  (char*)sB + (i * 256 + tid) * 16);
    }
    __syncthreads();   // vmcnt(0) drain + barrier: tile ready
#pragma unroll
    for (int kk = 0; kk < 2; kk++) {
      int s = kk * 4 + (lane >> 4);
      bf16x8 a[4], b[4];
#pragma unroll
      for (int mf = 0; mf < 4; mf++)
        a[mf] = lds_frag(sA, wm * 64 + mf * 16 + (lane & 15), s);
#pragma unroll
      for (int nf = 0; nf < 4; nf++)
        b[nf] = lds_frag(sB, wn * 64 + nf * 16 + (lane & 15), s);
#pragma unroll
      for (int mf = 0; mf < 4; mf++)
#pragma unroll
        for (int nf = 0; nf < 4; nf++)
          acc[mf][nf] = __builtin_amdgcn_mfma_f32_16x16x32_bf16(a[mf], b[nf], acc[mf][nf], 0, 0, 0);
    }
    __syncthreads();   // all reads done; LDS free for next stage
  }

  // epilogue: nf pairs (W1,W3) -> silu(g)*u
  int cb = (n0i >> 1) + wn * 32 + (lane & 15);
#pragma unroll
  for (int mf = 0; mf < 4; mf++)
#pragma unroll
    for (int v = 0; v < 4; v++) {
      int r = r0 + wm * 64 + mf * 16 + (lane >> 4) * 4 + v;
      if (r >= rend) continue;
#pragma unroll
      for (int p = 0; p < 2; p++) {
        float g = acc[mf][2 * p][v], u = acc[mf][2 * p + 1][v];
        float hv = g / (1.f + __expf(-g)) * u;
        H[(size_t)r * D + cb + p * 16] = f2bf(hv);
      }
    }
}

// ---- GEMM2: tile 128(M) x 128(N), BK=64, 4 waves 2x2, wave 64x64,
// single-buffered (32 KB, 4 blocks/CU). Writes RAW per-slot rows Y. ----
__global__ __launch_bounds__(256, 4) void gemm2_k(
    const ushort* __restrict__ Hm, const ushort* __restrict__ W2t,
    ushort* __restrict__ Y, const int* __restrict__ meta) {
  __shared__ ushort sA[128 * 64];
  __shared__ ushort sB[128 * 64];
  int tm = blockIdx.y;
  if (tm >= meta[0]) return;
  int e = meta[16 + tm], r0 = meta[96 + tm], rend = meta[176 + tm];
  int n0 = blockIdx.x * 128;
  int tid = threadIdx.x, lane = tid & 63, wid = tid >> 6;
  int wm = wid >> 1, wn = wid & 1;

  const char* gH = (const char*)Hm;
  const char* gB = (const char*)(W2t + (size_t)e * D * D);

  int prow = tid >> 3, pslot = tid & 7;
  size_t arow[4];
  int brow[4], phys[4];
#pragma unroll
  for (int i = 0; i < 4; i++) {
    int row = i * 32 + prow;
    int gr = r0 + row; if (gr > N_SLOTS - 1) gr = N_SLOTS - 1;
    arow[i] = (size_t)gr * 2048;
    brow[i] = n0 + row;
    phys[i] = (pslot ^ (row & 7)) * 16;
  }

  f32x4 acc[4][4] = {};

  for (int kt = 0; kt < NKT; kt++) {
    int kb = kt * 128;
#pragma unroll
    for (int i = 0; i < 4; i++) {
      gload_lds16(gH + arow[i] + kb + phys[i], (char*)sA + (i * 256 + tid) * 16);
      gload_lds16(gB + (size_t)brow[i] * 2048 + kb + phys[i],
                  (char*)sB + (i * 256 + tid) * 16);
    }
    __syncthreads();
#pragma unroll
    for (int kk = 0; kk < 2; kk++) {
      int s = kk * 4 + (lane >> 4);
      bf16x8 a[4], b[4];
#pragma unroll
      for (int mf = 0; mf < 4; mf++)
        a[mf] = lds_frag(sA, wm * 64 + mf * 16 + (lane & 15), s);
#pragma unroll
      for (int nf = 0; nf < 4; nf++)
        b[nf] = lds_frag(sB, wn * 64 + nf * 16 + (lane & 15), s);
#pragma unroll
      for (int mf = 0; mf < 4; mf++)
#pragma unroll
        for (int nf = 0; nf < 4; nf++)
          acc[mf][nf] = __builtin_amdgcn_mfma_f32_16x16x32_bf16(a[mf], b[nf], acc[mf][nf], 0, 0, 0);
    }
    __syncthreads();
  }

#pragma unroll
  for (int mf = 0; mf < 4; mf++)
#pragma unroll
    for (int v = 0; v < 4; v++) {
      int r = r0 + wm * 64 + mf * 16 + (lane >> 4) * 4 + v;
      if (r >= rend) continue;
#pragma unroll
      for (int nf = 0; nf < 4; nf++)
        Y[(size_t)r * D + n0 + wn * 64 + nf * 16 + (lane & 15)] = f2bf(acc[mf][nf][v]);
    }
}

// ---- combine: out[t] = ew[2t]*Y[smap[2t]] + ew[2t+1]*Y[smap[2t+1]] ----
__global__ void combine_k(const ushort* __restrict__ Y, const int* __restrict__ smap,
                          const float* __restrict__ ew, float* __restrict__ out) {
  int tkn = blockIdx.x * 4 + (threadIdx.x >> 6);
  int lane = threadIdx.x & 63;
  int p0 = smap[2 * tkn], p1 = smap[2 * tkn + 1];
  float w0 = ew[2 * tkn], w1 = ew[2 * tkn + 1];
  const ushort4* y0 = (const ushort4*)(Y + (size_t)p0 * D);
  const ushort4* y1 = (const ushort4*)(Y + (size_t)p1 * D);
  float4* o = (float4*)(out + (size_t)tkn * D);
#pragma unroll
  for (int j = 0; j < 4; j++) {
    int c = j * 64 + lane;
    ushort4 a = y0[c], b = y1[c];
    float4 v;
    v.x = w0 * bf2f(a.x) + w1 * bf2f(b.x);
    v.y = w0 * bf2f(a.y) + w1 * bf2f(b.y);
    v.z = w0 * bf2f(a.z) + w1 * bf2f(b.z);
    v.w = w0 * bf2f(a.w) + w1 * bf2f(b.w);
    o[c] = v;
  }
}

extern "C" void kernel_launch(void* const* d_in, const int* in_sizes, int n_in,
                              void* d_out, int out_size, void* d_ws, size_t ws_size,
                              hipStream_t stream) {
  const float* x  = (const float*)d_in[0];
  const float* ew = (const float*)d_in[1];
  const int*   ei = (const int*)d_in[2];
  const float* w1 = (const float*)d_in[3];
  const float* w3 = (const float*)d_in[4];
  const float* w2 = (const float*)d_in[5];
  float* out = (float*)d_out;

  char* ws = (char*)d_ws;
  int*    meta = (int*)ws;                            // 4 KB
  int*    tok  = (int*)(ws + 4096);                   // 32 KB
  int*    smap = (int*)(ws + 4096 + 32768);           // 32 KB
  ushort* Xbf  = (ushort*)(ws + (1ull << 20));        // [1,9) MB (token order)
  ushort* W13t = (ushort*)(ws + (9ull << 20));        // [9,41) MB (interleaved)
  ushort* W2t  = (ushort*)(ws + (41ull << 20));       // [41,57) MB (by gemm1 front)
  ushort* Hm   = (ushort*)(ws + (57ull << 20));       // [57,73) MB (slot order)
  // Y overlays Xbf + W13t head: both dead once gemm1 completes (stream order)
  ushort* Ym   = (ushort*)(ws + (1ull << 20));        // [1,17) MB

  prep_k<<<4353, 256, 0, stream>>>(x, ei, ew, w1, w3,
                                   out + (size_t)N_TOKENS * D, meta, tok, smap,
                                   Xbf, W13t);
  gemm1_k<<<dim3(16, NTRB + MAXT), 256, 0, stream>>>(Xbf, W13t, Hm, tok, meta, w2, W2t);
  gemm2_k<<<dim3(8, MAXT), 256, 0, stream>>>(Hm, W2t, Ym, meta);
  combine_k<<<N_TOKENS / 4, 256, 0, stream>>>(Ym, smap, ew, out);
}

// Round 6
// 115.476 us; speedup vs baseline: 1.1907x; 1.0064x over previous
//
#include <hip/hip_runtime.h>
#include <cstdint>

#define D 1024
#define N_TOKENS 4096
#define N_SLOTS 8192
#define NEXP 8
#define NKT 16          // 1024 / BK(=64)
#define MAXT 80         // max 128-row tiles: 64 + 7 boundary
#define NTRF 8          // W2-transpose front y-rows (x16 = 128 blocks x 16 tiles)

typedef float f32x4 __attribute__((ext_vector_type(4)));
typedef __bf16 bf16x8 __attribute__((ext_vector_type(8)));
typedef __attribute__((address_space(3))) uint32_t lds_u32;
typedef __attribute__((address_space(1))) const uint32_t glb_u32;

__device__ __forceinline__ void gload_lds16(const void* g, void* l) {
  __builtin_amdgcn_global_load_lds((glb_u32*)g, (lds_u32*)l, 16, 0, 0);
}

__device__ __forceinline__ ushort f2bf(float f) {
  union { float f; uint32_t u; } c; c.f = f;
  uint32_t u = c.u;
  return (ushort)((u + 0x7FFFu + ((u >> 16) & 1u)) >> 16);
}

__device__ __forceinline__ float bf2f(ushort u) {
  union { uint32_t u; float f; } c; c.u = (uint32_t)u << 16;
  return c.f;
}

__device__ __forceinline__ bf16x8 lds_frag(const ushort* base, int row, int s) {
  return *(const bf16x8*)((const char*)base + row * 128 + ((s ^ (row & 7)) * 16));
}

// TPAD=66: transpose-tile row stride = 132 B = 33 banks (odd) -> the
// column-read (row step 4 per lane) spreads over 16 banks (4-way) instead of
// the 16-way conflict that stride 72 (36 banks, even) produced.
#define TPAD 66

// ---------------- fused prologue: routing + x-cast + W1/W3 transpose --------
// block 0: routing; blocks 1..256: cast x fp32->bf16 (token order);
// blocks 257..4352: W1/W3 transpose (fp32 [e][k][n] -> bf16 [e][n'][k] interleave)
// W2 transpose lives in gemm1 FRONT blocks (128 pipelined blocks).
__global__ void prep_k(const float* __restrict__ x, const int* __restrict__ ei,
                       const float* __restrict__ ew,
                       const float* __restrict__ w1, const float* __restrict__ w3,
                       float* __restrict__ hist_out, int* __restrict__ meta,
                       int* __restrict__ tok, int* __restrict__ smap,
                       ushort* __restrict__ Xbf, ushort* __restrict__ w13t) {
  int bid = blockIdx.x, t = threadIdx.x;
  if (bid == 0) {
    // deterministic routing: per-thread counts over contiguous 32-slot chunks
    __shared__ int cmat[256][8];   // 8 KB
    __shared__ int off[NEXP + 1];
#pragma unroll
    for (int e = 0; e < NEXP; e++) cmat[t][e] = 0;
    int base = t * 32;
#pragma unroll 4
    for (int j = 0; j < 32; j++) cmat[t][ei[base + j]]++;
    __syncthreads();
    if (t < NEXP) {
      int run = 0;
      for (int i = 0; i < 256; i++) { int v = cmat[i][t]; cmat[i][t] = run; run += v; }
      meta[8 + t] = run;   // expert totals (temp)
    }
    __syncthreads();
    if (t == 0) {
      int s = 0;
      for (int e = 0; e < NEXP; e++) { off[e] = s; s += meta[8 + e]; }
      off[NEXP] = s;
      int nt = 0;
      for (int e = 0; e < NEXP; e++)
        for (int r = off[e]; r < off[e + 1]; r += 128)
          if (nt < MAXT) {
            meta[16 + nt] = e;
            meta[96 + nt] = r;
            int re = off[e + 1]; if (r + 128 < re) re = r + 128;
            meta[176 + nt] = re;
            nt++;
          }
      meta[0] = nt;
      for (int e = 0; e < NEXP; e++) hist_out[e] = (float)meta[8 + e];
    }
    __syncthreads();
    // deterministic scatter; also record inverse map slot -> position
#pragma unroll 4
    for (int j = 0; j < 32; j++) {
      int slot = base + j;
      int e = ei[slot];
      int p = off[e] + cmat[t][e]++;
      tok[p] = slot >> 1;
      smap[slot] = p;
    }
  } else if (bid <= 256) {
    // cast x -> bf16, token order. 16384 elems per block.
    int cb = bid - 1;
    const float4* xs = (const float4*)x + (size_t)cb * 4096;
    ushort4* xd = (ushort4*)Xbf + (size_t)cb * 4096;
#pragma unroll
    for (int i = 0; i < 16; i++) {
      float4 v = xs[i * 256 + t];
      ushort4 o;
      o.x = f2bf(v.x); o.y = f2bf(v.y); o.z = f2bf(v.z); o.w = f2bf(v.w);
      xd[i * 256 + t] = o;
    }
  } else {
    int wb = bid - 257;
    int z = wb >> 8, rem = wb & 255;
    int kb = rem >> 4, nb = rem & 15;
    int which = z >> 3, e = z & 7;           // which: 0=W1, 1=W3
    const float* src = (which == 0 ? w1 : w3) + (size_t)e * D * D;
    ushort* dst = w13t + (size_t)e * 2048 * D;
    __shared__ ushort tile[64][TPAD];
    int k0 = kb * 64, n0 = nb * 64;
    int r = t >> 4, c = t & 15;
#pragma unroll
    for (int rep = 0; rep < 4; rep++) {
      int krow = rep * 16 + r;
      float4 v = *(const float4*)(src + (size_t)(k0 + krow) * D + n0 + c * 4);
      tile[krow][c * 4 + 0] = f2bf(v.x);
      tile[krow][c * 4 + 1] = f2bf(v.y);
      tile[krow][c * 4 + 2] = f2bf(v.z);
      tile[krow][c * 4 + 3] = f2bf(v.w);
    }
    __syncthreads();
#pragma unroll
    for (int rep = 0; rep < 4; rep++) {
      int lr = rep * 16 + r;
      int nrow = n0 + lr;
      ushort4 o;
      o.x = tile[c * 4 + 0][lr];
      o.y = tile[c * 4 + 1][lr];
      o.z = tile[c * 4 + 2][lr];
      o.w = tile[c * 4 + 3][lr];
      int crow = ((nrow >> 4) << 5) + ((which == 1) ? 16 : 0) + (nrow & 15);
      *(ushort4*)(dst + (size_t)crow * D + k0 + c * 4) = o;
    }
  }
}

// ---- GEMM1: tile 128(M) x 128(Ni), BK=64, 4 waves 2x2, wave 64x64,
// single-buffered LDS (32 KB) for 4 blocks/CU TLP latency hiding (proven
// 687 TF = the 2-phase grouped ceiling; dbuf+vmcnt regressed, see R1).
// Grid FRONT (blockIdx.y < NTRF): W2 fp32->bf16 transpose, 128 blocks x 16
// tiles with 2-deep software pipelining (tile i+1's global loads issued
// during tile i's store phase -> HBM latency hidden). Cost model: tax ~=
// n_blk x dur / capacity + BW contention, SUBJECT TO per-block dur << GEMM
// drain (~50 us). R3: 256x10us ok (6 us tax); R4: 2048x1tile = serial prefix
// (10 us); R5: 64x64us VIOLATED the constraint (transpose became critical
// path, gemm1=70us). 128 x ~16us pipelined satisfies both margins. ----
__global__ __launch_bounds__(256, 4) void gemm1_k(
    const ushort* __restrict__ Xbf, const ushort* __restrict__ W13t,
    ushort* __restrict__ H, const int* __restrict__ tok,
    const int* __restrict__ meta,
    const float* __restrict__ w2, ushort* __restrict__ W2t) {
  __shared__ ushort sA[128 * 64];
  __shared__ ushort sB[128 * 64];
  int tm = blockIdx.y;
  int tid = threadIdx.x;

  if (tm < NTRF) {
    // ---- W2 transpose front-path: one (expert, k-strip) per block,
    // 16 n-tiles, 2-deep pipelined ----
    int gid = tm * 16 + blockIdx.x;                    // 0..127
    int e = gid >> 4, kb = gid & 15;
    const float* src = w2 + (size_t)e * D * D;
    ushort* dst = W2t + (size_t)e * D * D;
    ushort (*tile)[TPAD] = (ushort(*)[TPAD])&sA[0];    // 8.25 KB overlay scratch
    int r = tid >> 4, c = tid & 15;
    int k0 = kb * 64;
    const float* sp = src + (size_t)k0 * D + c * 4;    // + krow*D + n0
    float4 va[4], vb[4];
#pragma unroll
    for (int rep = 0; rep < 4; rep++)
      va[rep] = *(const float4*)(sp + (size_t)(rep * 16 + r) * D);   // tile 0
    for (int i = 0; i < 16; i += 2) {
      __syncthreads();                       // prev store-phase reads done
#pragma unroll
      for (int rep = 0; rep < 4; rep++) {    // write tile i (waits va loads)
        int krow = rep * 16 + r;
        tile[krow][c * 4 + 0] = f2bf(va[rep].x);
        tile[krow][c * 4 + 1] = f2bf(va[rep].y);
        tile[krow][c * 4 + 2] = f2bf(va[rep].z);
        tile[krow][c * 4 + 3] = f2bf(va[rep].w);
      }
      if (i + 1 < 16)                        // issue tile i+1 loads (async)
#pragma unroll
        for (int rep = 0; rep < 4; rep++)
          vb[rep] = *(const float4*)(sp + (size_t)(rep * 16 + r) * D + (i + 1) * 64);
      __syncthreads();                       // tile i ready in LDS
      {
        int n0 = i * 64;
#pragma unroll
        for (int rep = 0; rep < 4; rep++) {
          int lr = rep * 16 + r;
          ushort4 o;
          o.x = tile[c * 4 + 0][lr];
          o.y = tile[c * 4 + 1][lr];
          o.z = tile[c * 4 + 2][lr];
          o.w = tile[c * 4 + 3][lr];
          *(ushort4*)(dst + (size_t)(n0 + lr) * D + k0 + c * 4) = o;
        }
      }
      __syncthreads();                       // tile i reads done
#pragma unroll
      for (int rep = 0; rep < 4; rep++) {    // write tile i+1 (waits vb loads)
        int krow = rep * 16 + r;
        tile[krow][c * 4 + 0] = f2bf(vb[rep].x);
        tile[krow][c * 4 + 1] = f2bf(vb[rep].y);
        tile[krow][c * 4 + 2] = f2bf(vb[rep].z);
        tile[krow][c * 4 + 3] = f2bf(vb[rep].w);
      }
      if (i + 2 < 16)                        // issue tile i+2 loads (async)
#pragma unroll
        for (int rep = 0; rep < 4; rep++)
          va[rep] = *(const float4*)(sp + (size_t)(rep * 16 + r) * D + (i + 2) * 64);
      __syncthreads();                       // tile i+1 ready in LDS
      {
        int n0 = (i + 1) * 64;
#pragma unroll
        for (int rep = 0; rep < 4; rep++) {
          int lr = rep * 16 + r;
          ushort4 o;
          o.x = tile[c * 4 + 0][lr];
          o.y = tile[c * 4 + 1][lr];
          o.z = tile[c * 4 + 2][lr];
          o.w = tile[c * 4 + 3][lr];
          *(ushort4*)(dst + (size_t)(n0 + lr) * D + k0 + c * 4) = o;
        }
      }
    }
    return;
  }
  tm -= NTRF;
  if (tm >= meta[0]) return;

  int e = meta[16 + tm], r0 = meta[96 + tm], rend = meta[176 + tm];
  int n0i = blockIdx.x * 128;
  int lane = tid & 63, wid = tid >> 6;
  int wm = wid >> 1, wn = wid & 1;

  const char* gX = (const char*)Xbf;
  const char* gB = (const char*)(W13t + (size_t)e * 2048 * D);

  int prow = tid >> 3, pslot = tid & 7;
  size_t arow[4];
  int brow[4], phys[4];
#pragma unroll
  for (int i = 0; i < 4; i++) {
    int row = i * 32 + prow;
    int gr = r0 + row; if (gr > N_SLOTS - 1) gr = N_SLOTS - 1;
    arow[i] = (size_t)tok[gr] * 2048;
    brow[i] = n0i + row;
    phys[i] = (pslot ^ (row & 7)) * 16;
  }

  f32x4 acc[4][4] = {};

  for (int kt = 0; kt < NKT; kt++) {
    int kb = kt * 128;
#pragma unroll
    for (int i = 0; i < 4; i++) {
      gload_lds16(gX + arow[i] + kb + phys[i], (char*)sA + (i * 256 + tid) * 16);
      gload_lds16(gB + (size_t)brow[i] * 2048 + kb + phys[i],
                  (char*)sB + (i * 256 + tid) * 16);
    }
    __syncthreads();   // vmcnt(0) drain + barrier: tile ready
#pragma unroll
    for (int kk = 0; kk < 2; kk++) {
      int s = kk * 4 + (lane >> 4);
      bf16x8 a[4], b[4];
#pragma unroll
      for (int mf = 0; mf < 4; mf++)
        a[mf] = lds_frag(sA, wm * 64 + mf * 16 + (lane & 15), s);
#pragma unroll
      for (int nf = 0; nf < 4; nf++)
        b[nf] = lds_frag(sB, wn * 64 + nf * 16 + (lane & 15), s);
#pragma unroll
      for (int mf = 0; mf < 4; mf++)
#pragma unroll
        for (int nf = 0; nf < 4; nf++)
          acc[mf][nf] = __builtin_amdgcn_mfma_f32_16x16x32_bf16(a[mf], b[nf], acc[mf][nf], 0, 0, 0);
    }
    __syncthreads();   // all reads done; LDS free for next stage
  }

  // epilogue: nf pairs (W1,W3) -> silu(g)*u
  int cb = (n0i >> 1) + wn * 32 + (lane & 15);
#pragma unroll
  for (int mf = 0; mf < 4; mf++)
#pragma unroll
    for (int v = 0; v < 4; v++) {
      int r = r0 + wm * 64 + mf * 16 + (lane >> 4) * 4 + v;
      if (r >= rend) continue;
#pragma unroll
      for (int p = 0; p < 2; p++) {
        float g = acc[mf][2 * p][v], u = acc[mf][2 * p + 1][v];
        float hv = g / (1.f + __expf(-g)) * u;
        H[(size_t)r * D + cb + p * 16] = f2bf(hv);
      }
    }
}

// ---- GEMM2: tile 128(M) x 128(N), BK=64, 4 waves 2x2, wave 64x64,
// single-buffered (32 KB, 4 blocks/CU). Writes RAW per-slot rows Y. ----
__global__ __launch_bounds__(256, 4) void gemm2_k(
    const ushort* __restrict__ Hm, const ushort* __restrict__ W2t,
    ushort* __restrict__ Y, const int* __restrict__ meta) {
  __shared__ ushort sA[128 * 64];
  __shared__ ushort sB[128 * 64];
  int tm = blockIdx.y;
  if (tm >= meta[0]) return;
  int e = meta[16 + tm], r0 = meta[96 + tm], rend = meta[176 + tm];
  int n0 = blockIdx.x * 128;
  int tid = threadIdx.x, lane = tid & 63, wid = tid >> 6;
  int wm = wid >> 1, wn = wid & 1;

  const char* gH = (const char*)Hm;
  const char* gB = (const char*)(W2t + (size_t)e * D * D);

  int prow = tid >> 3, pslot = tid & 7;
  size_t arow[4];
  int brow[4], phys[4];
#pragma unroll
  for (int i = 0; i < 4; i++) {
    int row = i * 32 + prow;
    int gr = r0 + row; if (gr > N_SLOTS - 1) gr = N_SLOTS - 1;
    arow[i] = (size_t)gr * 2048;
    brow[i] = n0 + row;
    phys[i] = (pslot ^ (row & 7)) * 16;
  }

  f32x4 acc[4][4] = {};

  for (int kt = 0; kt < NKT; kt++) {
    int kb = kt * 128;
#pragma unroll
    for (int i = 0; i < 4; i++) {
      gload_lds16(gH + arow[i] + kb + phys[i], (char*)sA + (i * 256 + tid) * 16);
      gload_lds16(gB + (size_t)brow[i] * 2048 + kb + phys[i],
                  (char*)sB + (i * 256 + tid) * 16);
    }
    __syncthreads();
#pragma unroll
    for (int kk = 0; kk < 2; kk++) {
      int s = kk * 4 + (lane >> 4);
      bf16x8 a[4], b[4];
#pragma unroll
      for (int mf = 0; mf < 4; mf++)
        a[mf] = lds_frag(sA, wm * 64 + mf * 16 + (lane & 15), s);
#pragma unroll
      for (int nf = 0; nf < 4; nf++)
        b[nf] = lds_frag(sB, wn * 64 + nf * 16 + (lane & 15), s);
#pragma unroll
      for (int mf = 0; mf < 4; mf++)
#pragma unroll
        for (int nf = 0; nf < 4; nf++)
          acc[mf][nf] = __builtin_amdgcn_mfma_f32_16x16x32_bf16(a[mf], b[nf], acc[mf][nf], 0, 0, 0);
    }
    __syncthreads();
  }

#pragma unroll
  for (int mf = 0; mf < 4; mf++)
#pragma unroll
    for (int v = 0; v < 4; v++) {
      int r = r0 + wm * 64 + mf * 16 + (lane >> 4) * 4 + v;
      if (r >= rend) continue;
#pragma unroll
      for (int nf = 0; nf < 4; nf++)
        Y[(size_t)r * D + n0 + wn * 64 + nf * 16 + (lane & 15)] = f2bf(acc[mf][nf][v]);
    }
}

// ---- combine: out[t] = ew[2t]*Y[smap[2t]] + ew[2t+1]*Y[smap[2t+1]] ----
__global__ void combine_k(const ushort* __restrict__ Y, const int* __restrict__ smap,
                          const float* __restrict__ ew, float* __restrict__ out) {
  int tkn = blockIdx.x * 4 + (threadIdx.x >> 6);
  int lane = threadIdx.x & 63;
  int p0 = smap[2 * tkn], p1 = smap[2 * tkn + 1];
  float w0 = ew[2 * tkn], w1 = ew[2 * tkn + 1];
  const ushort4* y0 = (const ushort4*)(Y + (size_t)p0 * D);
  const ushort4* y1 = (const ushort4*)(Y + (size_t)p1 * D);
  float4* o = (float4*)(out + (size_t)tkn * D);
#pragma unroll
  for (int j = 0; j < 4; j++) {
    int c = j * 64 + lane;
    ushort4 a = y0[c], b = y1[c];
    float4 v;
    v.x = w0 * bf2f(a.x) + w1 * bf2f(b.x);
    v.y = w0 * bf2f(a.y) + w1 * bf2f(b.y);
    v.z = w0 * bf2f(a.z) + w1 * bf2f(b.z);
    v.w = w0 * bf2f(a.w) + w1 * bf2f(b.w);
    o[c] = v;
  }
}

extern "C" void kernel_launch(void* const* d_in, const int* in_sizes, int n_in,
                              void* d_out, int out_size, void* d_ws, size_t ws_size,
                              hipStream_t stream) {
  const float* x  = (const float*)d_in[0];
  const float* ew = (const float*)d_in[1];
  const int*   ei = (const int*)d_in[2];
  const float* w1 = (const float*)d_in[3];
  const float* w3 = (const float*)d_in[4];
  const float* w2 = (const float*)d_in[5];
  float* out = (float*)d_out;

  char* ws = (char*)d_ws;
  int*    meta = (int*)ws;                            // 4 KB
  int*    tok  = (int*)(ws + 4096);                   // 32 KB
  int*    smap = (int*)(ws + 4096 + 32768);           // 32 KB
  ushort* Xbf  = (ushort*)(ws + (1ull << 20));        // [1,9) MB (token order)
  ushort* W13t = (ushort*)(ws + (9ull << 20));        // [9,41) MB (interleaved)
  ushort* W2t  = (ushort*)(ws + (41ull << 20));       // [41,57) MB (by gemm1 front)
  ushort* Hm   = (ushort*)(ws + (57ull << 20));       // [57,73) MB (slot order)
  // Y overlays Xbf + W13t head: both dead once gemm1 completes (stream order)
  ushort* Ym   = (ushort*)(ws + (1ull << 20));        // [1,17) MB

  prep_k<<<4353, 256, 0, stream>>>(x, ei, ew, w1, w3,
                                   out + (size_t)N_TOKENS * D, meta, tok, smap,
                                   Xbf, W13t);
  gemm1_k<<<dim3(16, NTRF + MAXT), 256, 0, stream>>>(Xbf, W13t, Hm, tok, meta, w2, W2t);
  gemm2_k<<<dim3(8, MAXT), 256, 0, stream>>>(Hm, W2t, Ym, meta);
  combine_k<<<N_TOKENS / 4, 256, 0, stream>>>(Ym, smap, ew, out);
}